// Round 1
// baseline (124.405 us; speedup 1.0000x reference)
//
#include <hip/hip_runtime.h>
#include <hip/hip_bf16.h>
#include <stdint.h>

typedef __attribute__((ext_vector_type(8))) __bf16 bf16x8;
typedef __attribute__((ext_vector_type(4))) float f32x4;

__device__ __forceinline__ unsigned short f2bf(float f) {
    unsigned u = __builtin_bit_cast(unsigned, f);
    return (unsigned short)((u + 0x7fffu + ((u >> 16) & 1u)) >> 16);  // RNE
}

__device__ __forceinline__ void glds16(const void* g, void* l) {
    __builtin_amdgcn_global_load_lds(
        (const __attribute__((address_space(1))) unsigned int*)(uintptr_t)g,
        (__attribute__((address_space(3))) unsigned int*)l, 16, 0, 0);
}

// ---------------------------------------------------------------------------
// Kernel 1: build G01[b][a0a1][o01][q] = F0[a0,o0,r0]*F1[a1,o1,r1]   (q=r0*2+r1)
//           and H23[b][o23][a2a3][q] = sum_{r2,r3} F2[a2,o2,r2]*F3[a3,o3,r3]
//                                      * core_flat[b, r3*8+r2*4+r1*2+r0]
// factors layout: [b][j][i][o][r] strides b:512 j:128 i:16 o:2 r:1
// ---------------------------------------------------------------------------
__global__ __launch_bounds__(256) void prep_tables(const float* __restrict__ factors,
                                                   const float* __restrict__ cores,
                                                   float* __restrict__ G01,
                                                   float* __restrict__ H23) {
    int idx = blockIdx.x * 256 + threadIdx.x;   // 0 .. 131071
    if (idx < 65536) {
        int q = idx & 3, o01 = (idx >> 2) & 63, a01 = (idx >> 8) & 63, b = idx >> 14;
        int r0 = q >> 1, r1 = q & 1;
        int o0 = o01 >> 3, o1 = o01 & 7, a0 = a01 >> 3, a1 = a01 & 7;
        G01[idx] = factors[b*512 +   0 + a0*16 + o0*2 + r0]
                 * factors[b*512 + 128 + a1*16 + o1*2 + r1];
    } else {
        int j = idx - 65536;
        int q = j & 3, a23 = (j >> 2) & 63, o23 = (j >> 8) & 63, b = j >> 14;
        int r0 = q >> 1, r1 = q & 1;
        int o2 = o23 >> 3, o3 = o23 & 7, a2 = a23 >> 3, a3 = a23 & 7;
        float s = 0.f;
#pragma unroll
        for (int r2 = 0; r2 < 2; ++r2)
#pragma unroll
            for (int r3 = 0; r3 < 2; ++r3)
                s += factors[b*512 + 256 + a2*16 + o2*2 + r2]
                   * factors[b*512 + 384 + a3*16 + o3*2 + r3]
                   * cores[b*16 + r3*8 + r2*4 + r1*2 + r0];
        H23[j] = s;   // j == ((b*64 + o23)*64 + a23)*4 + q
    }
}

// ---------------------------------------------------------------------------
// Kernel 2: convert x (f32) -> bf16
// ---------------------------------------------------------------------------
__global__ __launch_bounds__(256) void cvt_bf16(const float4* __restrict__ in,
                                                ushort4* __restrict__ out) {
    int i = blockIdx.x * 256 + threadIdx.x;     // exactly 1048576 threads
    float4 v = in[i];
    ushort4 o;
    o.x = f2bf(v.x); o.y = f2bf(v.y); o.z = f2bf(v.z); o.w = f2bf(v.w);
    out[i] = o;
}

// ---------------------------------------------------------------------------
// Kernel 3: Wt[o][i] (bf16, row-major, stride 4096)
//   o = o01*64 + o23, i = a01*64 + a23
//   Wt = sum_{b,q} G01[b][a01][o01][q] * H23[b][o23][a23][q]
// grid 512: w = pgrp(16) + 16*lgrp(32). Thread owns one (o23,a23) pair,
// holds H23 slice in 16 regs; G01 slab for lgrp's 2 a01 values staged in LDS.
// ---------------------------------------------------------------------------
__global__ __launch_bounds__(256) void build_w(const float* __restrict__ G01,
                                               const float* __restrict__ H23,
                                               unsigned short* __restrict__ Wt) {
    __shared__ float gs[2048];                  // [b][a'(2)][o01(64)][q(4)]
    const int w = blockIdx.x;
    const int pgrp = w & 15, lgrp = w >> 4;     // lgrp 0..31
    const int tid = threadIdx.x;
#pragma unroll
    for (int rep = 0; rep < 2; ++rep) {
        int j = (rep * 256 + tid) * 4;          // flat gs index
        int b = j >> 9, a = (j >> 8) & 1, rest = j & 255;
        *(float4*)&gs[j] = *(const float4*)&G01[((b * 64 + lgrp * 2 + a) << 8) + rest];
    }
    __syncthreads();
    const int p = pgrp * 256 + tid;
    const int o23 = p >> 6, a23 = p & 63;
    const float4 h0 = *(const float4*)&H23[(( 0 + o23) * 64 + a23) * 4];
    const float4 h1 = *(const float4*)&H23[((64 + o23) * 64 + a23) * 4];
    const float4 h2 = *(const float4*)&H23[((128 + o23) * 64 + a23) * 4];
    const float4 h3 = *(const float4*)&H23[((192 + o23) * 64 + a23) * 4];
    for (int it = 0; it < 128; ++it) {
        int a = it >> 6, o01 = it & 63;
        const float* gp = &gs[a * 256 + (o01 << 2)];
        float v = gp[0]    * h0.x + gp[1]    * h0.y + gp[2]    * h0.z + gp[3]    * h0.w
                + gp[512]  * h1.x + gp[513]  * h1.y + gp[514]  * h1.z + gp[515]  * h1.w
                + gp[1024] * h2.x + gp[1025] * h2.y + gp[1026] * h2.z + gp[1027] * h2.w
                + gp[1536] * h3.x + gp[1537] * h3.y + gp[1538] * h3.z + gp[1539] * h3.w;
        int a01 = lgrp * 2 + a;
        Wt[(size_t)(o01 * 64 + o23) * 4096 + (a01 * 64 + a23)] = f2bf(v);
    }
}

// ---------------------------------------------------------------------------
// Kernel 4: C[1024][4096] = A[1024][4096] * Wt^T  (Wt is [N=4096][K=4096] bf16)
// m97-structure: 128x128 tile, BK=32, 4 waves (2x2), 16x16x32 bf16 MFMA,
// global_load_lds width-16 staging, 2-barrier main loop.
// ---------------------------------------------------------------------------
__global__ __launch_bounds__(256) void gemm_bt(const unsigned short* __restrict__ A,
                                               const unsigned short* __restrict__ Bt,
                                               float* __restrict__ C) {
    constexpr int K = 4096;
    constexpr int N = 4096;
    __shared__ alignas(16) unsigned short As[128 * 32];
    __shared__ alignas(16) unsigned short Bs[128 * 32];
    const int tid = threadIdx.x;
    const int bm = blockIdx.x >> 5;             // 0..7
    const int bn = blockIdx.x & 31;             // 0..31
    const int wid = tid >> 6, lane = tid & 63;
    const int wm = wid >> 1, wn = wid & 1;

    // staging: thread t loads 8 bf16 from row (t>>2), col ((t&3)*8) of the tile
    const int srow = tid >> 2;
    const int scol = (tid & 3) << 3;
    const unsigned short* gA0 = A  + (size_t)(bm * 128 + srow) * K + scol;
    const unsigned short* gB0 = Bt + (size_t)(bn * 128 + srow) * K + scol;
    char* lA = (char*)As + wid * 1024;          // wave-uniform LDS base
    char* lB = (char*)Bs + wid * 1024;

    const int fr = lane & 15, fh = lane >> 4;
    const char* pA = (const char*)As + (wm * 64 + fr) * 64 + fh * 16;
    const char* pB = (const char*)Bs + (wn * 64 + fr) * 64 + fh * 16;

    f32x4 acc[4][4] = {};

    for (int kt = 0; kt < K; kt += 32) {
        glds16(gA0 + kt, lA);
        glds16(gA0 + 64 * K + kt, lA + 4096);
        glds16(gB0 + kt, lB);
        glds16(gB0 + 64 * K + kt, lB + 4096);
        __syncthreads();                         // drains vmcnt -> tiles ready
        bf16x8 af[4], bfr[4];
#pragma unroll
        for (int i = 0; i < 4; ++i) af[i]  = *(const bf16x8*)(pA + i * 1024);
#pragma unroll
        for (int i = 0; i < 4; ++i) bfr[i] = *(const bf16x8*)(pB + i * 1024);
#pragma unroll
        for (int mi = 0; mi < 4; ++mi)
#pragma unroll
            for (int ni = 0; ni < 4; ++ni)
                acc[mi][ni] = __builtin_amdgcn_mfma_f32_16x16x32_bf16(
                    af[mi], bfr[ni], acc[mi][ni], 0, 0, 0);
        __syncthreads();                         // all reads done before next stage
    }

    const int crow0 = bm * 128 + wm * 64 + fh * 4;
    const int ccol0 = bn * 128 + wn * 64 + fr;
#pragma unroll
    for (int mi = 0; mi < 4; ++mi)
#pragma unroll
        for (int ni = 0; ni < 4; ++ni)
#pragma unroll
            for (int j = 0; j < 4; ++j)
                C[(size_t)(crow0 + mi * 16 + j) * N + (ccol0 + ni * 16)] = acc[mi][ni][j];
}

// ---------------------------------------------------------------------------
extern "C" void kernel_launch(void* const* d_in, const int* in_sizes, int n_in,
                              void* d_out, int out_size, void* d_ws, size_t ws_size,
                              hipStream_t stream) {
    const float* inputs  = (const float*)d_in[0];   // [1024, 4096] f32
    const float* cores   = (const float*)d_in[1];   // [4, 16] f32
    const float* factors = (const float*)d_in[2];   // [4,4,8,8,2] f32
    float* out = (float*)d_out;                     // [1024, 4096] f32

    char* ws = (char*)d_ws;
    unsigned short* xb = (unsigned short*)ws;                       //  8 MB bf16 x
    unsigned short* Wt = (unsigned short*)(ws + (8u << 20));        // 32 MB bf16 W^T
    float* G01 = (float*)(ws + (40u << 20));                        // 256 KB
    float* H23 = G01 + 65536;                                       // 256 KB

    prep_tables<<<512, 256, 0, stream>>>(factors, cores, G01, H23);
    cvt_bf16<<<4096, 256, 0, stream>>>((const float4*)inputs, (ushort4*)xb);
    build_w<<<512, 256, 0, stream>>>(G01, H23, Wt);
    gemm_bt<<<256, 256, 0, stream>>>(xb, Wt, out);
}